// Round 2
// baseline (25308.755 us; speedup 1.0000x reference)
//
#include <hip/hip_runtime.h>
#include <hip/hip_fp16.h>
#include <math.h>

typedef _Float16 f16;
typedef _Float16 f16x2 __attribute__((ext_vector_type(2)));
typedef _Float16 f16x4 __attribute__((ext_vector_type(4)));
typedef _Float16 f16x8 __attribute__((ext_vector_type(8)));
typedef float f32x2 __attribute__((ext_vector_type(2)));
typedef float f32x4 __attribute__((ext_vector_type(4)));
typedef unsigned int u32;

#define NLAYER 3
#define BB 64           // combined batch (32 code + 32 comment)
#define TT 512          // seq len
#define HH 256          // hidden per direction
#define GG 768          // 3*H
#define EE 512          // per-layer input dim (=2H)
#define ROWS (BB*TT)    // 32768

// ---------------- helpers ----------------
__device__ __forceinline__ void load_lds16(const void* g, void* l) {
  __builtin_amdgcn_global_load_lds((const __attribute__((address_space(1))) u32*)g,
                                   (__attribute__((address_space(3))) u32*)l, 16, 0, 0);
}

// packed f32 FMA (VOP3P, gfx90a+): d.x=a.x*b.x+c.x ; d.y=a.y*b.y+c.y
__device__ __forceinline__ f32x2 pk_fma(f32x2 a, f32x2 b, f32x2 c) {
  f32x2 d;
  asm("v_pk_fma_f32 %0, %1, %2, %3" : "=v"(d) : "v"(a), "v"(b), "v"(c));
  return d;
}

// ---------------- K0: Wx -> f16 hi/lo split, pre-transposed ----------------
// Bth/Btl[l][n][k],  n = dir*768+j  (k-contiguous rows = GEMM B^T layout)
__global__ __launch_bounds__(256) void prep_wx(
    const float* __restrict__ Wx, f16* __restrict__ Bth, f16* __restrict__ Btl)
{
  const int n_bt = NLAYER * 2 * GG * EE;     // 2,359,296
  const int stride = gridDim.x * blockDim.x;
  for (int e = blockIdx.x * blockDim.x + threadIdx.x; e < n_bt; e += stride) {
    int l = e / (2 * GG * EE); int r = e % (2 * GG * EE);
    int n = r / EE; int k = r % EE;
    int dr = n / GG; int j = n % GG;
    float w = Wx[(((size_t)(l * 2 + dr) * EE + k) * GG) + j];
    f16 hi = (f16)w;
    Bth[e] = hi;
    Btl[e] = (f16)(w - (float)hi);
  }
}

// ---------------- K1: embedding gather -> Xh/Xl f16 [32768][512] ----------------
__global__ __launch_bounds__(128) void gather_embed(
    const int* __restrict__ code_idx, const int* __restrict__ comment_idx,
    const float* __restrict__ table, f16* __restrict__ Xh, f16* __restrict__ Xl)
{
  const int r = blockIdx.x;  // rows 0..16383 = code, rest = comment
  const int idx = (r < 16384) ? code_idx[r] : comment_idx[r - 16384];
  const float4 v = ((const float4*)(table + (size_t)idx * EE))[threadIdx.x];
  f16x4 hi, lo;
  hi.x = (f16)v.x; lo.x = (f16)(v.x - (float)hi.x);
  hi.y = (f16)v.y; lo.y = (f16)(v.y - (float)hi.y);
  hi.z = (f16)v.z; lo.z = (f16)(v.z - (float)hi.z);
  hi.w = (f16)v.w; lo.w = (f16)(v.w - (float)hi.w);
  *(f16x4*)(Xh + (size_t)r * EE + threadIdx.x * 4) = hi;
  *(f16x4*)(Xl + (size_t)r * EE + threadIdx.x * 4) = lo;
}

// ---------------- K2: xp = (Ah+Al) @ (Bh+Bl)^T -> f32 [32768][1536] ----------------
// 128x128 tile, BK=64, split-2 f16: acc += ah*bh + al*bh + ah*bl  (al*bl ~2^-24, dropped)
__global__ __launch_bounds__(256) void gemm_split(
    const f16* __restrict__ Ah, const f16* __restrict__ Al,
    const f16* __restrict__ Bh, const f16* __restrict__ Bl,
    float* __restrict__ C)
{
  __shared__ __align__(16) f16 sAh[128 * 64];
  __shared__ __align__(16) f16 sAl[128 * 64];
  __shared__ __align__(16) f16 sBh[128 * 64];
  __shared__ __align__(16) f16 sBl[128 * 64];
  const int wg = blockIdx.x;
  const int nt = wg % 12;               // 12 col tiles (1536/128)
  const int mt = wg / 12;
  const int t = threadIdx.x;
  const int lane = t & 63, wid = t >> 6;
  const int wr = wid >> 1, wc = wid & 1;

  f32x4 acc[4][4] = {};

  for (int ks_ = 0; ks_ < EE / 64; ++ks_) {
    const int k0 = ks_ * 64;
    if (ks_) __syncthreads();
    #pragma unroll
    for (int c = 0; c < 4; ++c) {
      const int s = c * 256 + t;          // 16B granule slot
      const int row = s >> 3;
      const int g = (s & 7) ^ (row & 7);  // swizzled source granule (T2 via source)
      const size_t offA = (size_t)(mt * 128 + row) * EE + k0 + g * 8;
      const size_t offB = (size_t)(nt * 128 + row) * EE + k0 + g * 8;
      load_lds16(Ah + offA, sAh + s * 8);
      load_lds16(Al + offA, sAl + s * 8);
      load_lds16(Bh + offB, sBh + s * 8);
      load_lds16(Bl + offB, sBl + s * 8);
    }
    asm volatile("s_waitcnt vmcnt(0)" ::: "memory");
    __syncthreads();

    #pragma unroll
    for (int kk = 0; kk < 2; ++kk) {
      f16x8 ah[4], al[4], bh[4], bl[4];
      #pragma unroll
      for (int m = 0; m < 4; ++m) {
        const int r = wr * 64 + m * 16 + (lane & 15);
        const int gr = (kk * 4 + (lane >> 4)) ^ (r & 7);
        ah[m] = *(const f16x8*)((const char*)sAh + r * 128 + gr * 16);
        al[m] = *(const f16x8*)((const char*)sAl + r * 128 + gr * 16);
        const int cb = wc * 64 + m * 16 + (lane & 15);
        const int gb = (kk * 4 + (lane >> 4)) ^ (cb & 7);
        bh[m] = *(const f16x8*)((const char*)sBh + cb * 128 + gb * 16);
        bl[m] = *(const f16x8*)((const char*)sBl + cb * 128 + gb * 16);
      }
      #pragma unroll
      for (int m = 0; m < 4; ++m)
        #pragma unroll
        for (int n = 0; n < 4; ++n) {
          acc[m][n] = __builtin_amdgcn_mfma_f32_16x16x32_f16(ah[m], bh[n], acc[m][n], 0, 0, 0);
          acc[m][n] = __builtin_amdgcn_mfma_f32_16x16x32_f16(al[m], bh[n], acc[m][n], 0, 0, 0);
          acc[m][n] = __builtin_amdgcn_mfma_f32_16x16x32_f16(ah[m], bl[n], acc[m][n], 0, 0, 0);
        }
    }
  }

  const int crow0 = mt * 128 + wr * 64 + (lane >> 4) * 4;
  const int ccol0 = nt * 128 + wc * 64 + (lane & 15);
  #pragma unroll
  for (int m = 0; m < 4; ++m)
    #pragma unroll
    for (int n = 0; n < 4; ++n)
      #pragma unroll
      for (int q = 0; q < 4; ++q)
        C[(size_t)(crow0 + m * 16 + q) * (2 * GG) + ccol0 + n * 16] = acc[m][n][q];
}

// ---------------- K3: GRU recurrence, full f32 ----------------
// 1024 threads per (batch,dir). thread (ks=t>>8, jj=t&255) owns Wh[k in ks*64..+64)
// for columns {jj, jj+256, jj+512} as 96 float2 VGPRs; dot via v_pk_fma_f32.
// h kept f32 in LDS (broadcast reads). 4-way K-split reduced via part[4][768].
__global__ __launch_bounds__(1024, 4) void gru_f32(
    const float* __restrict__ xp,     // [32768][1536]
    const float* __restrict__ Wh,     // layer base: [2][256][768] f32
    const float* __restrict__ bias,   // [2][2][768]
    f16* __restrict__ Xh, f16* __restrict__ Xl,   // [32768][512] (l<2)
    float* __restrict__ states,       // [64][512]  (l==2)
    int last)
{
  const int wg = blockIdx.x;     // 0..127
  const int dir = wg >> 6, b = wg & 63;
  const int t = threadIdx.x;
  const int ks = t >> 8, jj = t & 255;

  __shared__ __align__(16) float hsm[HH];
  __shared__ float part[4][GG];
  __shared__ float gs[2 * HH];
  __shared__ float xhs[HH];
  __shared__ float rhs[HH];

  // resident recurrent weights (f32, exact)
  f32x2 w0[32], w1[32], w2[32];
  {
    const float* wb = Wh + (size_t)dir * (HH * GG) + (size_t)(ks * 64) * GG;
    #pragma unroll
    for (int m = 0; m < 32; ++m) {
      w0[m] = f32x2{wb[(2 * m) * GG + jj      ], wb[(2 * m + 1) * GG + jj      ]};
      w1[m] = f32x2{wb[(2 * m) * GG + jj + 256], wb[(2 * m + 1) * GG + jj + 256]};
      w2[m] = f32x2{wb[(2 * m) * GG + jj + 512], wb[(2 * m + 1) * GG + jj + 512]};
    }
  }
  float b0 = 0.f, b1 = 0.f, xcur = 0.f;
  const float* xbase = xp + (size_t)b * TT * (2 * GG) + dir * GG;
  if (t < GG) {
    b0 = bias[dir * 2 * GG + t];
    b1 = bias[dir * 2 * GG + GG + t];
    xcur = xbase[(size_t)(dir ? TT - 1 : 0) * (2 * GG) + t];
  }
  float hreg = 0.f;
  if (t < HH) hsm[t] = 0.f;
  __syncthreads();

  for (int st = 0; st < TT; ++st) {
    const int tt = dir ? (TT - 1 - st) : st;
    // --- Phase A: 4-way-K-split dot (96 pk_fma), h broadcast from LDS ---
    f32x2 a0 = {0.f, 0.f}, a1 = {0.f, 0.f}, a2 = {0.f, 0.f};
    const float4* hp = (const float4*)hsm + ks * 16;
    #pragma unroll
    for (int m = 0; m < 16; ++m) {
      const float4 q = hp[m];
      const f32x2 qa = {q.x, q.y}, qb = {q.z, q.w};
      a0 = pk_fma(qa, w0[2 * m], a0); a0 = pk_fma(qb, w0[2 * m + 1], a0);
      a1 = pk_fma(qa, w1[2 * m], a1); a1 = pk_fma(qb, w1[2 * m + 1], a1);
      a2 = pk_fma(qa, w2[2 * m], a2); a2 = pk_fma(qb, w2[2 * m + 1], a2);
    }
    part[ks][jj]       = a0.x + a0.y;
    part[ks][jj + 256] = a1.x + a1.y;
    part[ks][jj + 512] = a2.x + a2.y;
    __syncthreads();
    // --- Phase B: reduce + gate preacts; prefetch next x ---
    if (t < GG) {
      const float red = part[0][t] + part[1][t] + part[2][t] + part[3][t] + b1;
      const float xb_ = xcur + b0;
      if (t < 2 * HH) gs[t] = xb_ + red;
      else { xhs[t - 2 * HH] = xb_; rhs[t - 2 * HH] = red; }
      if (st + 1 < TT) {
        const int ttn = dir ? (tt - 1) : (tt + 1);
        xcur = xbase[(size_t)ttn * (2 * GG) + t];
      }
    }
    __syncthreads();
    // --- Phase C: gates + state update (precise transcendentals) ---
    if (t < HH) {
      const float z = 1.f / (1.f + expf(-gs[t]));
      const float r = 1.f / (1.f + expf(-gs[HH + t]));
      const float hh = tanhf(xhs[t] + r * rhs[t]);
      hreg = z * hreg + (1.f - z) * hh;
      hsm[t] = hreg;
      if (!last) {
        const f16 hi = (f16)hreg;
        const size_t o = (size_t)(b * TT + tt) * EE + dir * HH + t;
        Xh[o] = hi;
        Xl[o] = (f16)(hreg - (float)hi);
      } else if (st == TT - 1) {
        states[(size_t)b * (2 * HH) + dir * HH + t] = hreg;
      }
    }
    __syncthreads();
  }
}

// ---------------- K4: leaks + BN1 + FC1 + BN2 + cls + sigmoid ----------------
__global__ __launch_bounds__(256) void final_head(
    const float* __restrict__ states, const float* __restrict__ leaks_in,
    const float* __restrict__ leaks_W, const float* __restrict__ leaks_b,
    const float* __restrict__ bn1g, const float* __restrict__ bn1b,
    const float* __restrict__ bn1m, const float* __restrict__ bn1v,
    const float* __restrict__ fc1W, const float* __restrict__ fc1b,
    const float* __restrict__ bn2g, const float* __restrict__ bn2b,
    const float* __restrict__ bn2m, const float* __restrict__ bn2v,
    const float* __restrict__ clsW, const float* __restrict__ clsb,
    float* __restrict__ out)
{
  const int b = blockIdx.x;   // 0..31
  const int c = threadIdx.x;  // 0..255
  __shared__ float vec[1280];
  __shared__ float red[256];

  float acc = leaks_b[c];
  for (int k = 0; k < 148; ++k) acc += leaks_in[b * 148 + k] * leaks_W[k * 256 + c];
  vec[1024 + c] = fmaxf(acc, 0.f);
  for (int i = c; i < 512; i += 256) {
    vec[i] = states[(size_t)b * 512 + i];              // code states
    vec[512 + i] = states[(size_t)(b + 32) * 512 + i]; // comment states
  }
  __syncthreads();
  for (int i = c; i < 1280; i += 256)
    vec[i] = (vec[i] - bn1m[i]) * rsqrtf(bn1v[i] + 1e-3f) * bn1g[i] + bn1b[i];
  __syncthreads();
  float a1 = fc1b[c];
  for (int i = 0; i < 1280; ++i) a1 += vec[i] * fc1W[i * 256 + c];
  a1 = fmaxf(a1, 0.f);
  a1 = (a1 - bn2m[c]) * rsqrtf(bn2v[c] + 1e-3f) * bn2g[c] + bn2b[c];
  red[c] = a1 * clsW[c];
  __syncthreads();
  for (int s = 128; s > 0; s >>= 1) { if (c < s) red[c] += red[c + s]; __syncthreads(); }
  if (c == 0) out[b] = 1.f / (1.f + expf(-(red[0] + clsb[0])));
}

// ---------------- launch ----------------
extern "C" void kernel_launch(void* const* d_in, const int* in_sizes, int n_in,
                              void* d_out, int out_size, void* d_ws, size_t ws_size,
                              hipStream_t stream) {
  const int*   comment_idx = (const int*)d_in[0];
  const int*   code_idx    = (const int*)d_in[2];
  const float* leaks_in    = (const float*)d_in[4];
  const float* table       = (const float*)d_in[6];
  const float* Wx          = (const float*)d_in[7];
  const float* Wh          = (const float*)d_in[8];
  const float* gb          = (const float*)d_in[9];
  const float* leaks_W     = (const float*)d_in[10];
  const float* leaks_b     = (const float*)d_in[11];
  const float* bn1g = (const float*)d_in[12];
  const float* bn1b = (const float*)d_in[13];
  const float* bn1m = (const float*)d_in[14];
  const float* bn1v = (const float*)d_in[15];
  const float* fc1W = (const float*)d_in[16];
  const float* fc1b = (const float*)d_in[17];
  const float* bn2g = (const float*)d_in[18];
  const float* bn2b = (const float*)d_in[19];
  const float* bn2m = (const float*)d_in[20];
  const float* bn2v = (const float*)d_in[21];
  const float* clsW = (const float*)d_in[22];
  const float* clsb = (const float*)d_in[23];
  float* out = (float*)d_out;

  // workspace layout (~266 MB)
  char* ws = (char*)d_ws;
  f16*   Xh     = (f16*)(ws);                       // 33,554,432 B
  f16*   Xl     = (f16*)(ws + 33554432);            // 33,554,432 B
  float* xp     = (float*)(ws + 67108864);          // 201,326,592 B (f32 [32768][1536])
  f16*   Bth    = (f16*)(ws + 268435456);           //  4,718,592 B
  f16*   Btl    = (f16*)(ws + 273154048);           //  4,718,592 B
  float* states = (float*)(ws + 277872640);         //    131,072 B

  prep_wx<<<dim3(1024), dim3(256), 0, stream>>>(Wx, Bth, Btl);
  gather_embed<<<dim3(ROWS), dim3(128), 0, stream>>>(code_idx, comment_idx, table, Xh, Xl);

  const int gemm_grid = (ROWS / 128) * (2 * GG / 128);  // 3072
  const size_t btl_stride = (size_t)2 * GG * EE;        // per-layer Bt elements
  const size_t wh_stride  = (size_t)2 * HH * GG;        // per-layer Wh elements

  for (int l = 0; l < NLAYER; ++l) {
    gemm_split<<<dim3(gemm_grid), dim3(256), 0, stream>>>(
        Xh, Xl, Bth + l * btl_stride, Btl + l * btl_stride, xp);
    gru_f32<<<dim3(128), dim3(1024), 0, stream>>>(
        xp, Wh + l * wh_stride, gb + l * 2 * 2 * GG,
        Xh, Xl, states, l == NLAYER - 1);
  }

  final_head<<<dim3(32), dim3(256), 0, stream>>>(states, leaks_in, leaks_W, leaks_b,
                                                 bn1g, bn1b, bn1m, bn1v, fc1W, fc1b,
                                                 bn2g, bn2b, bn2m, bn2v, clsW, clsb, out);
}

// Round 3
// 3499.354 us; speedup vs baseline: 7.2324x; 7.2324x over previous
//
#include <hip/hip_runtime.h>
#include <hip/hip_fp16.h>
#include <math.h>

typedef _Float16 f16;
typedef _Float16 f16x2 __attribute__((ext_vector_type(2)));
typedef _Float16 f16x4 __attribute__((ext_vector_type(4)));
typedef _Float16 f16x8 __attribute__((ext_vector_type(8)));
typedef float f32x2 __attribute__((ext_vector_type(2)));
typedef float f32x4 __attribute__((ext_vector_type(4)));
typedef unsigned int u32;
typedef unsigned long long u64;

#define NLAYER 3
#define BB 64           // combined batch (32 code + 32 comment)
#define TT 512          // seq len
#define HH 256          // hidden per direction
#define GG 768          // 3*H
#define EE 512          // per-layer input dim (=2H)
#define ROWS (BB*TT)    // 32768

// ---------------- helpers ----------------
__device__ __forceinline__ void load_lds16(const void* g, void* l) {
  __builtin_amdgcn_global_load_lds((const __attribute__((address_space(1))) u32*)g,
                                   (__attribute__((address_space(3))) u32*)l, 16, 0, 0);
}

// packed f32 FMA (VOP3P, gfx90a+): d.x=a.x*b.x+c.x ; d.y=a.y*b.y+c.y
__device__ __forceinline__ f32x2 pk_fma(f32x2 a, f32x2 b, f32x2 c) {
  f32x2 d;
  asm("v_pk_fma_f32 %0, %1, %2, %3" : "=v"(d) : "v"(a), "v"(b), "v"(c));
  return d;
}

// self-tagged 64-bit exchange word: hi32 = tag, lo32 = f32 payload.
// RELAXED device-scope atomics: tag+data travel together, no fence needed.
__device__ __forceinline__ void publish(u64* p, u32 tag, float v) {
  u64 e = ((u64)tag << 32) | (u64)__builtin_bit_cast(u32, v);
  __hip_atomic_store(p, e, __ATOMIC_RELAXED, __HIP_MEMORY_SCOPE_AGENT);
}
__device__ __forceinline__ float wait_peer(const u64* p, u32 tag) {
  u64 e;
  for (;;) {
    e = __hip_atomic_load(p, __ATOMIC_RELAXED, __HIP_MEMORY_SCOPE_AGENT);
    if ((u32)(e >> 32) == tag) break;
    __builtin_amdgcn_s_sleep(2);
  }
  return __builtin_bit_cast(float, (u32)e);
}

// ---------------- K0: Wx -> f16 hi/lo split, pre-transposed ----------------
__global__ __launch_bounds__(256) void prep_wx(
    const float* __restrict__ Wx, f16* __restrict__ Bth, f16* __restrict__ Btl)
{
  const int n_bt = NLAYER * 2 * GG * EE;     // 2,359,296
  const int stride = gridDim.x * blockDim.x;
  for (int e = blockIdx.x * blockDim.x + threadIdx.x; e < n_bt; e += stride) {
    int l = e / (2 * GG * EE); int r = e % (2 * GG * EE);
    int n = r / EE; int k = r % EE;
    int dr = n / GG; int j = n % GG;
    float w = Wx[(((size_t)(l * 2 + dr) * EE + k) * GG) + j];
    f16 hi = (f16)w;
    Bth[e] = hi;
    Btl[e] = (f16)(w - (float)hi);
  }
}

// ---------------- K1: embedding gather -> Xh/Xl f16 [32768][512] ----------------
__global__ __launch_bounds__(128) void gather_embed(
    const int* __restrict__ code_idx, const int* __restrict__ comment_idx,
    const float* __restrict__ table, f16* __restrict__ Xh, f16* __restrict__ Xl)
{
  const int r = blockIdx.x;  // rows 0..16383 = code, rest = comment
  const int idx = (r < 16384) ? code_idx[r] : comment_idx[r - 16384];
  const float4 v = ((const float4*)(table + (size_t)idx * EE))[threadIdx.x];
  f16x4 hi, lo;
  hi.x = (f16)v.x; lo.x = (f16)(v.x - (float)hi.x);
  hi.y = (f16)v.y; lo.y = (f16)(v.y - (float)hi.y);
  hi.z = (f16)v.z; lo.z = (f16)(v.z - (float)hi.z);
  hi.w = (f16)v.w; lo.w = (f16)(v.w - (float)hi.w);
  *(f16x4*)(Xh + (size_t)r * EE + threadIdx.x * 4) = hi;
  *(f16x4*)(Xl + (size_t)r * EE + threadIdx.x * 4) = lo;
}

// ---------------- K2: xp = (Ah+Al) @ (Bh+Bl)^T -> f32 [32768][1536] ----------------
__global__ __launch_bounds__(256) void gemm_split(
    const f16* __restrict__ Ah, const f16* __restrict__ Al,
    const f16* __restrict__ Bh, const f16* __restrict__ Bl,
    float* __restrict__ C)
{
  __shared__ __align__(16) f16 sAh[128 * 64];
  __shared__ __align__(16) f16 sAl[128 * 64];
  __shared__ __align__(16) f16 sBh[128 * 64];
  __shared__ __align__(16) f16 sBl[128 * 64];
  const int wg = blockIdx.x;
  const int nt = wg % 12;
  const int mt = wg / 12;
  const int t = threadIdx.x;
  const int lane = t & 63, wid = t >> 6;
  const int wr = wid >> 1, wc = wid & 1;

  f32x4 acc[4][4] = {};

  for (int ks_ = 0; ks_ < EE / 64; ++ks_) {
    const int k0 = ks_ * 64;
    if (ks_) __syncthreads();
    #pragma unroll
    for (int c = 0; c < 4; ++c) {
      const int s = c * 256 + t;
      const int row = s >> 3;
      const int g = (s & 7) ^ (row & 7);
      const size_t offA = (size_t)(mt * 128 + row) * EE + k0 + g * 8;
      const size_t offB = (size_t)(nt * 128 + row) * EE + k0 + g * 8;
      load_lds16(Ah + offA, sAh + s * 8);
      load_lds16(Al + offA, sAl + s * 8);
      load_lds16(Bh + offB, sBh + s * 8);
      load_lds16(Bl + offB, sBl + s * 8);
    }
    asm volatile("s_waitcnt vmcnt(0)" ::: "memory");
    __syncthreads();

    #pragma unroll
    for (int kk = 0; kk < 2; ++kk) {
      f16x8 ah[4], al[4], bh[4], bl[4];
      #pragma unroll
      for (int m = 0; m < 4; ++m) {
        const int r = wr * 64 + m * 16 + (lane & 15);
        const int gr = (kk * 4 + (lane >> 4)) ^ (r & 7);
        ah[m] = *(const f16x8*)((const char*)sAh + r * 128 + gr * 16);
        al[m] = *(const f16x8*)((const char*)sAl + r * 128 + gr * 16);
        const int cb = wc * 64 + m * 16 + (lane & 15);
        const int gb = (kk * 4 + (lane >> 4)) ^ (cb & 7);
        bh[m] = *(const f16x8*)((const char*)sBh + cb * 128 + gb * 16);
        bl[m] = *(const f16x8*)((const char*)sBl + cb * 128 + gb * 16);
      }
      #pragma unroll
      for (int m = 0; m < 4; ++m)
        #pragma unroll
        for (int n = 0; n < 4; ++n) {
          acc[m][n] = __builtin_amdgcn_mfma_f32_16x16x32_f16(ah[m], bh[n], acc[m][n], 0, 0, 0);
          acc[m][n] = __builtin_amdgcn_mfma_f32_16x16x32_f16(al[m], bh[n], acc[m][n], 0, 0, 0);
          acc[m][n] = __builtin_amdgcn_mfma_f32_16x16x32_f16(ah[m], bl[n], acc[m][n], 0, 0, 0);
        }
    }
  }

  const int crow0 = mt * 128 + wr * 64 + (lane >> 4) * 4;
  const int ccol0 = nt * 128 + wc * 64 + (lane & 15);
  #pragma unroll
  for (int m = 0; m < 4; ++m)
    #pragma unroll
    for (int n = 0; n < 4; ++n)
      #pragma unroll
      for (int q = 0; q < 4; ++q)
        C[(size_t)(crow0 + m * 16 + q) * (2 * GG) + ccol0 + n * 16] = acc[m][n][q];
}

// ---------------- K3: GRU recurrence, f32-exact, one (b,dir) split over 2 CUs ----------------
// 256 WGs x 512 threads. WG w: job = w&127 (dir,b), kh = w>>7 (K-half).
// Thread (sub=t>>8, jj=t&255) owns Wh[k in kh*128+sub*64 ..+64) x cols {jj,jj+256,jj+512}
// = 192 f32 in VGPRs (launch_bounds(512,2) -> 256-VGPR cap, 1 WG/CU, all 256 resident).
// Per step: local partial dot -> publish peer's 384 needed cols as self-tagged u64
// atomics -> poll peer's partials -> gates -> update own 128-wide h slice.
__global__ __launch_bounds__(512, 2) void gru_pair(
    const float* __restrict__ xp,     // [32768][1536]
    const float* __restrict__ Wh,     // layer base: [2][256][768] f32
    const float* __restrict__ bias,   // [2][2][768]
    f16* __restrict__ Xh, f16* __restrict__ Xl,   // [32768][512] (l<2)
    float* __restrict__ states,       // [64][512]  (l==2)
    u64* __restrict__ xchg,           // [128 jobs][2 kh][2 parity][384]
    int last, int layer)
{
  const int w = blockIdx.x;          // 0..255 ; pair (w, w+128) same XCD under round-robin
  const int job = w & 127;
  const int kh  = w >> 7;
  const int dir = job >> 6, b = job & 63;
  const int t = threadIdx.x;
  const int sub = t >> 8, jj = t & 255;

  __shared__ __align__(16) float hsm[128];   // my K-half's h slice
  __shared__ float part[2][GG];
  __shared__ float prez[128], prer[128], xh_s[128], rh_s[128];

  // resident recurrent weights (f32, exact): 192 regs
  f32x2 w0[32], w1[32], w2[32];
  {
    const float* wb = Wh + (size_t)dir * (HH * GG) + (size_t)(kh * 128 + sub * 64) * GG;
    #pragma unroll
    for (int m = 0; m < 32; ++m) {
      w0[m] = f32x2{wb[(2 * m) * GG + jj      ], wb[(2 * m + 1) * GG + jj      ]};
      w1[m] = f32x2{wb[(2 * m) * GG + jj + 256], wb[(2 * m + 1) * GG + jj + 256]};
      w2[m] = f32x2{wb[(2 * m) * GG + jj + 512], wb[(2 * m + 1) * GG + jj + 512]};
    }
  }

  // gate-thread setup (t<384): g = gate block, jjg = j within my half
  const int g = t >> 7, jjg = t & 127;
  const int colm = g * 256 + kh * 128 + jjg;        // col I consume
  const int colp = g * 256 + (1 - kh) * 128 + jjg;  // col I publish for peer
  float b0c = 0.f, b1c = 0.f, xcur = 0.f;
  const float* xpb = xp + (size_t)b * TT * (2 * GG) + dir * GG;
  if (t < 384) {
    b0c = bias[dir * 2 * GG + colm];
    b1c = bias[dir * 2 * GG + GG + colm];
    xcur = xpb[(size_t)(dir ? TT - 1 : 0) * (2 * GG) + colm];
  }
  u64* pub = xchg + (size_t)(job * 2 + kh) * 2 * 384;
  const u64* peer = xchg + (size_t)(job * 2 + (1 - kh)) * 2 * 384;

  float hreg = 0.f;
  if (t < 128) hsm[t] = 0.f;
  __syncthreads();

  for (int st = 0; st < TT; ++st) {
    const int tt = dir ? (TT - 1 - st) : st;
    const u32 tag = (u32)(layer * TT + st + 1);   // unique per (layer,step); != 0xAAAAAAAA poison
    const int par = st & 1;

    // --- dot over my 64-k slice (96 pk_fma), h broadcast from LDS ---
    f32x2 a0 = {0.f, 0.f}, a1 = {0.f, 0.f}, a2 = {0.f, 0.f};
    const float4* hp = (const float4*)hsm + sub * 16;
    #pragma unroll
    for (int m = 0; m < 16; ++m) {
      const float4 q = hp[m];
      const f32x2 qa = {q.x, q.y}, qb = {q.z, q.w};
      a0 = pk_fma(qa, w0[2 * m], a0); a0 = pk_fma(qb, w0[2 * m + 1], a0);
      a1 = pk_fma(qa, w1[2 * m], a1); a1 = pk_fma(qb, w1[2 * m + 1], a1);
      a2 = pk_fma(qa, w2[2 * m], a2); a2 = pk_fma(qb, w2[2 * m + 1], a2);
    }
    part[sub][jj]       = a0.x + a0.y;
    part[sub][jj + 256] = a1.x + a1.y;
    part[sub][jj + 512] = a2.x + a2.y;
    __syncthreads();

    // --- exchange + gate preacts (threads 0..383) ---
    if (t < 384) {
      publish(pub + par * 384 + t, tag, part[0][colp] + part[1][colp]);
      float xnext = 0.f;
      if (st + 1 < TT) xnext = xpb[(size_t)(dir ? tt - 1 : tt + 1) * (2 * GG) + colm];
      const float mine = part[0][colm] + part[1][colm];
      const float pv = wait_peer(peer + par * 384 + t, tag);
      const float rec = mine + pv + b1c;
      const float xpre = xcur + b0c;
      if (g == 0)      prez[jjg] = xpre + rec;
      else if (g == 1) prer[jjg] = xpre + rec;
      else           { xh_s[jjg] = xpre; rh_s[jjg] = rec; }
      xcur = xnext;
    }
    __syncthreads();

    // --- state update for my 128-wide slice ---
    if (t < 128) {
      const float z = 1.f / (1.f + expf(-prez[t]));
      const float r = 1.f / (1.f + expf(-prer[t]));
      const float hh = tanhf(xh_s[t] + r * rh_s[t]);
      hreg = z * hreg + (1.f - z) * hh;
      hsm[t] = hreg;
      const int j = kh * 128 + t;
      if (!last) {
        const f16 hi = (f16)hreg;
        const size_t o = (size_t)(b * TT + tt) * EE + dir * HH + j;
        Xh[o] = hi;
        Xl[o] = (f16)(hreg - (float)hi);
      } else if (st == TT - 1) {
        states[(size_t)b * (2 * HH) + dir * HH + j] = hreg;
      }
    }
    __syncthreads();
  }
}

// ---------------- K4: leaks + BN1 + FC1 + BN2 + cls + sigmoid ----------------
__global__ __launch_bounds__(256) void final_head(
    const float* __restrict__ states, const float* __restrict__ leaks_in,
    const float* __restrict__ leaks_W, const float* __restrict__ leaks_b,
    const float* __restrict__ bn1g, const float* __restrict__ bn1b,
    const float* __restrict__ bn1m, const float* __restrict__ bn1v,
    const float* __restrict__ fc1W, const float* __restrict__ fc1b,
    const float* __restrict__ bn2g, const float* __restrict__ bn2b,
    const float* __restrict__ bn2m, const float* __restrict__ bn2v,
    const float* __restrict__ clsW, const float* __restrict__ clsb,
    float* __restrict__ out)
{
  const int b = blockIdx.x;   // 0..31
  const int c = threadIdx.x;  // 0..255
  __shared__ float vec[1280];
  __shared__ float red[256];

  float acc = leaks_b[c];
  for (int k = 0; k < 148; ++k) acc += leaks_in[b * 148 + k] * leaks_W[k * 256 + c];
  vec[1024 + c] = fmaxf(acc, 0.f);
  for (int i = c; i < 512; i += 256) {
    vec[i] = states[(size_t)b * 512 + i];
    vec[512 + i] = states[(size_t)(b + 32) * 512 + i];
  }
  __syncthreads();
  for (int i = c; i < 1280; i += 256)
    vec[i] = (vec[i] - bn1m[i]) * rsqrtf(bn1v[i] + 1e-3f) * bn1g[i] + bn1b[i];
  __syncthreads();
  float a1 = fc1b[c];
  for (int i = 0; i < 1280; ++i) a1 += vec[i] * fc1W[i * 256 + c];
  a1 = fmaxf(a1, 0.f);
  a1 = (a1 - bn2m[c]) * rsqrtf(bn2v[c] + 1e-3f) * bn2g[c] + bn2b[c];
  red[c] = a1 * clsW[c];
  __syncthreads();
  for (int s = 128; s > 0; s >>= 1) { if (c < s) red[c] += red[c + s]; __syncthreads(); }
  if (c == 0) out[b] = 1.f / (1.f + expf(-(red[0] + clsb[0])));
}

// ---------------- launch ----------------
extern "C" void kernel_launch(void* const* d_in, const int* in_sizes, int n_in,
                              void* d_out, int out_size, void* d_ws, size_t ws_size,
                              hipStream_t stream) {
  const int*   comment_idx = (const int*)d_in[0];
  const int*   code_idx    = (const int*)d_in[2];
  const float* leaks_in    = (const float*)d_in[4];
  const float* table       = (const float*)d_in[6];
  const float* Wx          = (const float*)d_in[7];
  const float* Wh          = (const float*)d_in[8];
  const float* gb          = (const float*)d_in[9];
  const float* leaks_W     = (const float*)d_in[10];
  const float* leaks_b     = (const float*)d_in[11];
  const float* bn1g = (const float*)d_in[12];
  const float* bn1b = (const float*)d_in[13];
  const float* bn1m = (const float*)d_in[14];
  const float* bn1v = (const float*)d_in[15];
  const float* fc1W = (const float*)d_in[16];
  const float* fc1b = (const float*)d_in[17];
  const float* bn2g = (const float*)d_in[18];
  const float* bn2b = (const float*)d_in[19];
  const float* bn2m = (const float*)d_in[20];
  const float* bn2v = (const float*)d_in[21];
  const float* clsW = (const float*)d_in[22];
  const float* clsb = (const float*)d_in[23];
  float* out = (float*)d_out;

  // workspace layout (~279.6 MB)
  char* ws = (char*)d_ws;
  f16*   Xh     = (f16*)(ws);                       //  33,554,432 B
  f16*   Xl     = (f16*)(ws + 33554432);            //  33,554,432 B
  float* xp     = (float*)(ws + 67108864);          // 201,326,592 B
  f16*   Bth    = (f16*)(ws + 268435456);           //   4,718,592 B
  f16*   Btl    = (f16*)(ws + 273154048);           //   4,718,592 B
  float* states = (float*)(ws + 277872640);         //     131,072 B
  u64*   xchg   = (u64*)(ws + 278003712);           //   1,572,864 B (no init needed: self-tagged)

  prep_wx<<<dim3(1024), dim3(256), 0, stream>>>(Wx, Bth, Btl);
  gather_embed<<<dim3(ROWS), dim3(128), 0, stream>>>(code_idx, comment_idx, table, Xh, Xl);

  const int gemm_grid = (ROWS / 128) * (2 * GG / 128);  // 3072
  const size_t btl_stride = (size_t)2 * GG * EE;
  const size_t wh_stride  = (size_t)2 * HH * GG;

  for (int l = 0; l < NLAYER; ++l) {
    gemm_split<<<dim3(gemm_grid), dim3(256), 0, stream>>>(
        Xh, Xl, Bth + l * btl_stride, Btl + l * btl_stride, xp);
    gru_pair<<<dim3(256), dim3(512), 0, stream>>>(
        xp, Wh + l * wh_stride, gb + l * 2 * 2 * GG,
        Xh, Xl, states, xchg, l == NLAYER - 1, l);
  }

  final_head<<<dim3(32), dim3(256), 0, stream>>>(states, leaks_in, leaks_W, leaks_b,
                                                 bn1g, bn1b, bn1m, bn1v, fc1W, fc1b,
                                                 bn2g, bn2b, bn2m, bn2v, clsW, clsb, out);
}